// Round 4
// baseline (746.416 us; speedup 1.0000x reference)
//
#include <hip/hip_runtime.h>

typedef __attribute__((ext_vector_type(8))) short bf16x8;
typedef __attribute__((ext_vector_type(4))) float f32x4;
typedef unsigned short u16;

#define NTOK    49
#define SCALE   0.17677669529663687f
#define NEGBIG  -30000.0f
#define DIV7(v) (((v) * 9363) >> 16)          // exact for 0..63

// ---- LDS layout (bytes). 16-B aligned sections.
// EX region: Q-xchg(49 rows x 512B, XOR-swizzled) -> K-xchg -> VT(256x56 u16)
//            -> P(4 x 49x72 u16)
// XO region: x-tile (49 rows x 512B, XOR-swizzled) -> O (same layout)
// Bias table: read directly from global (L1/L2-resident, 2.7KB) - not staged.
#define EX_OFF     0
#define XCHG_END   25088     // 49 * 512
#define EX_BYTES   28704     // >= VT 28,672 + 16B row-255 overread; 16B-mult
#define XO_OFF     28704
#define XO_BYTES   25088     // 49 * 512
#define SMEM_BYTES 53792     // <= 54,613 -> 3 blocks/CU (160KB/3)

// Row-XOR swizzle: stride 512B is 0 mod 32 banks; XOR row bits into the 16-B
// slot index -> 16 rows spread across 8 bank-groups x2 = 2-way (free, m136).
// Applied on BOTH write and read sides (all traffic is reg-staged).
#define SWZ(row, byteoff) ((byteoff) ^ (((row) & 7) << 4))

static __device__ __forceinline__ float b2f(u16 u) {
    return __uint_as_float(((unsigned int)u) << 16);
}
static __device__ __forceinline__ u16 f2b(float f) {
    unsigned int x = __float_as_uint(f);
    x += 0x7fffu + ((x >> 16) & 1u);      // RNE
    return (u16)(x >> 16);
}
static __device__ __forceinline__ bf16x8 load8(const void* base, int eidx, int isbf) {
    if (isbf) return *(const bf16x8*)((const u16*)base + eidx);
    const float* f = (const float*)base + eidx;
    float4 a = *(const float4*)f;
    float4 c = *(const float4*)(f + 4);
    bf16x8 r;
    r[0] = (short)f2b(a.x); r[1] = (short)f2b(a.y); r[2] = (short)f2b(a.z); r[3] = (short)f2b(a.w);
    r[4] = (short)f2b(c.x); r[5] = (short)f2b(c.y); r[6] = (short)f2b(c.z); r[7] = (short)f2b(c.w);
    return r;
}
static __device__ __forceinline__ float loadf(const void* base, int i, int isbf) {
    return isbf ? b2f(((const u16*)base)[i]) : ((const float*)base)[i];
}
static __device__ __forceinline__ int region9(int gh, int gw) {
    return (gh < 49 ? 0 : (gh < 53 ? 1 : 2)) * 3 + (gw < 49 ? 0 : (gw < 53 ? 1 : 2));
}

__global__ void __launch_bounds__(256, 3)
swin_fused_v6(const void* __restrict__ x, const void* __restrict__ qkv_w,
              const void* __restrict__ qkv_b, const void* __restrict__ proj_w,
              const void* __restrict__ proj_b, const void* __restrict__ bias_tbl,
              void* __restrict__ out)
{
    __shared__ __align__(16) char smem[SMEM_BYTES];
    const int tid    = threadIdx.x;
    const int wv     = tid >> 6;
    const int lane   = tid & 63;
    const int lane15 = lane & 15;
    const int quad   = lane >> 4;
    const int crow   = quad << 2;

    const int win  = blockIdx.x;
    const int b    = win >> 6;
    const int wrem = win & 63;
    const int whi  = wrem >> 3;
    const int wwi  = wrem & 7;

    // ---- dtype sniff (wave-uniform, identical samples in every wave) ----
    int good = 0;
#pragma unroll
    for (int j = 0; j < 8; ++j) {
        u16 u = ((const u16*)qkv_w)[lane * 32 + j * 4];
        int e = (u >> 7) & 0xff;
        good += (e == 0 || (e >= 100 && e <= 140)) ? 1 : 0;
    }
#pragma unroll
    for (int d = 1; d < 64; d <<= 1) good += __shfl_xor(good, d, 64);
    const int isbf = (good > 300) ? 1 : 0;   // 512 samples: bf16 ~512, f32 ~90

    // ---- stage 0: gather x -> XO (swizzled), zero VT-only tail of EX ----
    for (int i = tid; i < NTOK * 32; i += 256) {
        int tok = i >> 5, ch = i & 31;
        int rt = DIV7(tok), ct = tok - rt * 7;
        int sh_ = whi * 7 + rt + 3; if (sh_ >= 56) sh_ -= 56;
        int sw_ = wwi * 7 + ct + 3; if (sw_ >= 56) sw_ -= 56;
        int idx = ((b * 56 + sh_) * 56 + sw_) * 256 + ch * 8;
        *(bf16x8*)(smem + XO_OFF + tok * 512 + SWZ(tok, ch * 16)) = load8(x, idx, isbf);
    }
    {
        // EX bytes [XCHG_END, EX_BYTES): VT channels >=224 junk-token cols and
        // the row-255 16B overread live here; never written by xchg or the
        // V-GEMM (tokens<49 only) -> must be finite (0 x NaN = NaN hazard).
        // Junk cols for ch<224 reuse stale xchg bytes = finite f2b output.
        bf16x8 z8 = {0, 0, 0, 0, 0, 0, 0, 0};
        for (int i = tid; i < (EX_BYTES - XCHG_END) / 16; i += 256)
            *(bf16x8*)(smem + EX_OFF + XCHG_END + i * 16) = z8;
    }
    __syncthreads();   // (a) x-tile + EX tail visible to all waves

    int mrowc[4];
#pragma unroll
    for (int t = 0; t < 4; ++t) {
        int m = t * 16 + lane15;
        mrowc[t] = m < 49 ? m : 48;
    }

    bf16x8 fragQ[2][4], fragK[2][4], fragV[2][4];

    // ---- rounds Q and K: GEMM into EX (wave-local columns), capture frags.
    // Wave wv writes exactly cols wv*64..wv*64+63 and captures from the same
    // range -> no cross-wave hazard (SWZ keeps bytes inside the wave's 128-B
    // window per row); within-wave RAW/WAR ordered by lgkmcnt.
    // No barriers in this loop: weight loads stay in flight across rounds.
#pragma unroll
    for (int rnd = 0; rnd < 2; ++rnd) {
        for (int ci = 0; ci < 4; ++ci) {
            int o = (wv * 4 + ci) * 16 + lane15;     // 0..255 (wave-local 64-col slice)
            int orow = rnd * 256 + o;
            f32x4 acc[4];
#pragma unroll
            for (int t = 0; t < 4; ++t) acc[t] = (f32x4){0.f, 0.f, 0.f, 0.f};
#pragma unroll
            for (int ks = 0; ks < 8; ++ks) {
                bf16x8 bfrag = load8(qkv_w, orow * 256 + ks * 32 + quad * 8, isbf);
                int cb = (ks * 32 + quad * 8) * 2;
#pragma unroll
                for (int tm = 0; tm < 4; ++tm) {
                    bf16x8 afrag = *(const bf16x8*)(smem + XO_OFF + mrowc[tm] * 512 + SWZ(mrowc[tm], cb));
                    acc[tm] = __builtin_amdgcn_mfma_f32_16x16x32_bf16(afrag, bfrag, acc[tm], 0, 0, 0);
                }
            }
            float bias = loadf(qkv_b, orow, isbf);
#pragma unroll
            for (int tm = 0; tm < 4; ++tm)
#pragma unroll
                for (int rr = 0; rr < 4; ++rr) {
                    int row = tm * 16 + crow + rr;
                    if (row < 49)
                        *(u16*)(smem + EX_OFF + row * 512 + SWZ(row, o * 2)) = f2b(acc[tm][rr] + bias);
                }
        }
#pragma unroll
        for (int hi = 0; hi < 2; ++hi)
#pragma unroll
            for (int t = 0; t < 4; ++t) {
                int cbyte = wv * 128 + hi * 64 + quad * 16;   // within wave's col slice
                bf16x8 f = *(const bf16x8*)(smem + EX_OFF + mrowc[t] * 512 + SWZ(mrowc[t], cbyte));
                if (rnd == 0) fragQ[hi][t] = f; else fragK[hi][t] = f;
            }
    }
    __syncthreads();   // (b) xchg dead in ALL waves before VT overwrites EX

    // ---- round V: GEMM into EX as V^T [256 ch][stride 56 u16], capture bv.
    // Channels are wave-local (wv*64..+63) for both write and capture.
    for (int ci = 0; ci < 4; ++ci) {
        int vch = (wv * 4 + ci) * 16 + lane15;       // 0..255
        int orow = 512 + vch;
        f32x4 acc[4];
#pragma unroll
        for (int t = 0; t < 4; ++t) acc[t] = (f32x4){0.f, 0.f, 0.f, 0.f};
#pragma unroll
        for (int ks = 0; ks < 8; ++ks) {
            bf16x8 bfrag = load8(qkv_w, orow * 256 + ks * 32 + quad * 8, isbf);
            int cb = (ks * 32 + quad * 8) * 2;
#pragma unroll
            for (int tm = 0; tm < 4; ++tm) {
                bf16x8 afrag = *(const bf16x8*)(smem + XO_OFF + mrowc[tm] * 512 + SWZ(mrowc[tm], cb));
                acc[tm] = __builtin_amdgcn_mfma_f32_16x16x32_bf16(afrag, bfrag, acc[tm], 0, 0, 0);
            }
        }
        float bias = loadf(qkv_b, orow, isbf);
#pragma unroll
        for (int tm = 0; tm < 4; ++tm)
#pragma unroll
            for (int rr = 0; rr < 4; ++rr) {
                int row = tm * 16 + crow + rr;
                if (row < 49)
                    *(u16*)(smem + EX_OFF + (vch * 56 + row) * 2) = f2b(acc[tm][rr] + bias);
            }
    }
#pragma unroll
    for (int hi = 0; hi < 2; ++hi)
#pragma unroll
        for (int f = 0; f < 4; ++f) {
            int vrow = wv * 64 + hi * 32 + (f & 1) * 16 + lane15;
            int vcol = (f >> 1) * 32 + quad * 8;     // cols >=49: stale-finite or zeroed pad
            fragV[hi][f] = *(const bf16x8*)(smem + EX_OFF + (vrow * 56 + vcol) * 2);
        }
    __syncthreads();   // (c) all bv captured before P overwrites EX; also the
                       //     last XO x-tile read precedes the first O write

    // ---- per-n (column) constants, head-independent ----
    int nval[4], regn_[4], idxn[4];
#pragma unroll
    for (int tn = 0; tn < 4; ++tn) {
        int n = tn * 16 + lane15;
        nval[tn] = (n < 49);
        int nc = n < 49 ? n : 48;
        int rn = DIV7(nc), cn = nc - rn * 7;
        regn_[tn] = region9(whi * 7 + rn, wwi * 7 + cn);
        idxn[tn]  = (6 - rn) * 13 + (6 - cn);
    }

    // ---- attention: 2 heads per wave; P overlays EX (per-wave slice) ----
    char* pbase = smem + EX_OFF + wv * 7056;
#pragma unroll
    for (int hi = 0; hi < 2; ++hi) {
        int h = wv * 2 + hi;
        f32x4 s[4][4];
#pragma unroll
        for (int tm = 0; tm < 4; ++tm)
#pragma unroll
            for (int tn = 0; tn < 4; ++tn) {
                f32x4 z = {0.f, 0.f, 0.f, 0.f};
                s[tm][tn] = __builtin_amdgcn_mfma_f32_16x16x32_bf16(fragQ[hi][tm], fragK[hi][tn], z, 0, 0, 0);
            }
#pragma unroll
        for (int tm = 0; tm < 4; ++tm)
#pragma unroll
            for (int rr = 0; rr < 4; ++rr) {
                int m = tm * 16 + crow + rr;
                int mc2 = m < 49 ? m : 48;
                int rm = DIV7(mc2), cm = mc2 - rm * 7;
                int regm = region9(whi * 7 + rm, wwi * 7 + cm);
                int basem = rm * 13 + cm;
                float e[4];
                float mv = NEGBIG;
#pragma unroll
                for (int tn = 0; tn < 4; ++tn) {
                    float v;
                    if (nval[tn]) {
                        int idx = basem + idxn[tn];
                        float bv = loadf(bias_tbl, idx * 8 + h, isbf);   // global: L1/L2-hot 2.7KB
                        v = s[tm][tn][rr] * SCALE + bv + ((regm != regn_[tn]) ? -100.0f : 0.0f);
                    } else v = NEGBIG;
                    e[tn] = v;
                    mv = fmaxf(mv, v);
                }
#pragma unroll
                for (int d = 1; d < 16; d <<= 1) mv = fmaxf(mv, __shfl_xor(mv, d, 16));
                float ssum = 0.f;
#pragma unroll
                for (int tn = 0; tn < 4; ++tn) {
                    e[tn] = __expf(e[tn] - mv);
                    ssum += e[tn];
                }
#pragma unroll
                for (int d = 1; d < 16; d <<= 1) ssum += __shfl_xor(ssum, d, 16);
                float ri = 1.0f / ssum;
                if (m < 49) {
#pragma unroll
                    for (int tn = 0; tn < 4; ++tn) {
                        int n = tn * 16 + lane15;
                        u16 hv = nval[tn] ? f2b(e[tn] * ri) : (u16)0;   // cols 49..63 exact 0
                        *(u16*)(pbase + (m * 72 + n) * 2) = hv;
                    }
                }
            }
        // P is wave-local (pbase per wv); within-wave write->read ordered by
        // lgkmcnt -> no barrier needed before PV.
        f32x4 ov0[4], ov1[4];
#pragma unroll
        for (int tm = 0; tm < 4; ++tm) {
            ov0[tm] = (f32x4){0.f, 0.f, 0.f, 0.f};
            ov1[tm] = (f32x4){0.f, 0.f, 0.f, 0.f};
        }
#pragma unroll
        for (int ks = 0; ks < 2; ++ks) {
            int kb = (ks * 32 + quad * 8) * 2;
#pragma unroll
            for (int tm = 0; tm < 4; ++tm) {
                bf16x8 ap = *(const bf16x8*)(pbase + mrowc[tm] * 144 + kb);
                ov0[tm] = __builtin_amdgcn_mfma_f32_16x16x32_bf16(ap, fragV[hi][ks * 2],     ov0[tm], 0, 0, 0);
                ov1[tm] = __builtin_amdgcn_mfma_f32_16x16x32_bf16(ap, fragV[hi][ks * 2 + 1], ov1[tm], 0, 0, 0);
            }
        }
        // O writes land in wave-local columns h*32..h*32+31 of XO (swizzled).
#pragma unroll
        for (int tm = 0; tm < 4; ++tm)
#pragma unroll
            for (int rr = 0; rr < 4; ++rr) {
                int row = tm * 16 + crow + rr;
                if (row < 49) {
                    *(u16*)(smem + XO_OFF + row * 512 + SWZ(row, (h * 32 + lane15) * 2))        = f2b(ov0[tm][rr]);
                    *(u16*)(smem + XO_OFF + row * 512 + SWZ(row, (h * 32 + 16 + lane15) * 2))   = f2b(ov1[tm][rr]);
                }
            }
    }
    __syncthreads();   // (d) O complete before proj reads all channels

    // ---- proj (transposed): out^T = proj_w x O^T; C rows=out-ch, cols=token ----
    int obase[4];
#pragma unroll
    for (int tn = 0; tn < 4; ++tn) {
        int n = tn * 16 + lane15;
        int nc = n < 49 ? n : 48;
        int rn = DIV7(nc), cn = nc - rn * 7;
        int dh = whi * 7 + rn + 3; if (dh >= 56) dh -= 56;
        int dw = wwi * 7 + cn + 3; if (dw >= 56) dw -= 56;
        obase[tn] = ((b * 56 + dh) * 56 + dw) * 256;
    }
    for (int ci = 0; ci < 4; ++ci) {
        int mch = wv * 4 + ci;                       // out-channel chunk 0..15
        f32x4 acc[4];
#pragma unroll
        for (int t = 0; t < 4; ++t) acc[t] = (f32x4){0.f, 0.f, 0.f, 0.f};
#pragma unroll
        for (int ks = 0; ks < 8; ++ks) {
            bf16x8 af = load8(proj_w, (mch * 16 + lane15) * 256 + ks * 32 + quad * 8, isbf);
            int cb = (ks * 32 + quad * 8) * 2;
#pragma unroll
            for (int tn = 0; tn < 4; ++tn) {
                bf16x8 bo = *(const bf16x8*)(smem + XO_OFF + mrowc[tn] * 512 + SWZ(mrowc[tn], cb));
                acc[tn] = __builtin_amdgcn_mfma_f32_16x16x32_bf16(af, bo, acc[tn], 0, 0, 0);
            }
        }
#pragma unroll
        for (int rr = 0; rr < 4; ++rr) {
            int ch = mch * 16 + crow + rr;           // lane-uniform
            float pb = loadf(proj_b, ch, isbf);
#pragma unroll
            for (int tn = 0; tn < 4; ++tn) {
                if (nval[tn]) {
                    float v = acc[tn][rr] + pb;
                    int oi = obase[tn] + ch;
                    if (isbf) ((u16*)out)[oi] = f2b(v);
                    else      ((float*)out)[oi] = v;
                }
            }
        }
    }
}

extern "C" void kernel_launch(void* const* d_in, const int* in_sizes, int n_in,
                              void* d_out, int out_size, void* d_ws, size_t ws_size,
                              hipStream_t stream) {
    (void)n_in; (void)d_ws; (void)ws_size; (void)out_size;
    int B = in_sizes[0] / (56 * 56 * 256);      // 32
    int nblk = B * 64;                          // one block per window

    swin_fused_v6<<<dim3(nblk), dim3(256), 0, stream>>>(
        d_in[0], d_in[1], d_in[2], d_in[3], d_in[4], d_in[5], d_out);
}

// Round 5
// 566.430 us; speedup vs baseline: 1.3178x; 1.3178x over previous
//
#include <hip/hip_runtime.h>

typedef __attribute__((ext_vector_type(8))) short bf16x8;
typedef __attribute__((ext_vector_type(4))) float f32x4;
typedef unsigned short u16;

#define NTOK    49
#define SCALE   0.17677669529663687f
#define NEGBIG  -30000.0f
#define DIV7(v) (((v) * 9363) >> 16)          // exact for 0..63

// ---- LDS layout (bytes). 16-B aligned sections.
// EX region: Q-xchg(49 rows x 512B, XOR-swizzled) -> K-xchg -> VT(256x56 u16)
//            -> P(4 x 49x72 u16)
// XO region: x-tile (49 rows x 512B, XOR-swizzled) -> O (same layout)
// BIAS: 169*8 u16 staged in LDS (global re-reads cost ~200MB FETCH in v6).
#define EX_OFF     0
#define XCHG_END   25088     // 49 * 512
#define EX_BYTES   28704     // >= VT 28,672 + 16B row-255 overread; 16B-mult
#define XO_OFF     28704
#define XO_BYTES   25088     // 49 * 512
#define BIAS_OFF   53792
#define BIAS_BYTES 2704
#define SMEM_BYTES 56496     // 2 blocks/CU; lb(256,2) keeps VGPR ~124, no spill

// Row-XOR swizzle: stride 512B is 0 mod 32 banks; XOR row bits into the 16-B
// slot index -> rows spread across bank groups (v6: conflicts -24% vs v5).
// Applied on BOTH write and read sides (all traffic is reg-staged).
#define SWZ(row, byteoff) ((byteoff) ^ (((row) & 7) << 4))

static __device__ __forceinline__ float b2f(u16 u) {
    return __uint_as_float(((unsigned int)u) << 16);
}
static __device__ __forceinline__ u16 f2b(float f) {
    unsigned int x = __float_as_uint(f);
    x += 0x7fffu + ((x >> 16) & 1u);      // RNE
    return (u16)(x >> 16);
}
static __device__ __forceinline__ bf16x8 load8(const void* base, int eidx, int isbf) {
    if (isbf) return *(const bf16x8*)((const u16*)base + eidx);
    const float* f = (const float*)base + eidx;
    float4 a = *(const float4*)f;
    float4 c = *(const float4*)(f + 4);
    bf16x8 r;
    r[0] = (short)f2b(a.x); r[1] = (short)f2b(a.y); r[2] = (short)f2b(a.z); r[3] = (short)f2b(a.w);
    r[4] = (short)f2b(c.x); r[5] = (short)f2b(c.y); r[6] = (short)f2b(c.z); r[7] = (short)f2b(c.w);
    return r;
}
static __device__ __forceinline__ float loadf(const void* base, int i, int isbf) {
    return isbf ? b2f(((const u16*)base)[i]) : ((const float*)base)[i];
}
static __device__ __forceinline__ int region9(int gh, int gw) {
    return (gh < 49 ? 0 : (gh < 53 ? 1 : 2)) * 3 + (gw < 49 ? 0 : (gw < 53 ? 1 : 2));
}

__global__ void __launch_bounds__(256, 2)
swin_fused_v7(const void* __restrict__ x, const void* __restrict__ qkv_w,
              const void* __restrict__ qkv_b, const void* __restrict__ proj_w,
              const void* __restrict__ proj_b, const void* __restrict__ bias_tbl,
              void* __restrict__ out)
{
    __shared__ __align__(16) char smem[SMEM_BYTES];
    const int tid    = threadIdx.x;
    const int wv     = tid >> 6;
    const int lane   = tid & 63;
    const int lane15 = lane & 15;
    const int quad   = lane >> 4;
    const int crow   = quad << 2;

    const int win  = blockIdx.x;
    const int b    = win >> 6;
    const int wrem = win & 63;
    const int whi  = wrem >> 3;
    const int wwi  = wrem & 7;

    // ---- dtype sniff (wave-uniform, identical samples in every wave) ----
    int good = 0;
#pragma unroll
    for (int j = 0; j < 8; ++j) {
        u16 u = ((const u16*)qkv_w)[lane * 32 + j * 4];
        int e = (u >> 7) & 0xff;
        good += (e == 0 || (e >= 100 && e <= 140)) ? 1 : 0;
    }
#pragma unroll
    for (int d = 1; d < 64; d <<= 1) good += __shfl_xor(good, d, 64);
    const int isbf = (good > 300) ? 1 : 0;   // 512 samples: bf16 ~512, f32 ~90

    // ---- stage 0: gather x -> XO (swizzled), bias -> LDS, zero EX VT tail ----
    for (int i = tid; i < NTOK * 32; i += 256) {
        int tok = i >> 5, ch = i & 31;
        int rt = DIV7(tok), ct = tok - rt * 7;
        int sh_ = whi * 7 + rt + 3; if (sh_ >= 56) sh_ -= 56;
        int sw_ = wwi * 7 + ct + 3; if (sw_ >= 56) sw_ -= 56;
        int idx = ((b * 56 + sh_) * 56 + sw_) * 256 + ch * 8;
        *(bf16x8*)(smem + XO_OFF + tok * 512 + SWZ(tok, ch * 16)) = load8(x, idx, isbf);
    }
    for (int i = tid; i < 169 * 8; i += 256)
        *(u16*)(smem + BIAS_OFF + i * 2) = f2b(loadf(bias_tbl, i, isbf));
    {
        // EX bytes [XCHG_END, EX_BYTES): VT channels >=224 junk-token cols and
        // the row-255 16B overread live here; never written by xchg or the
        // V-GEMM (tokens<49 only) -> must be finite (0 x NaN = NaN hazard).
        // Junk cols for ch<224 reuse stale xchg bytes = finite f2b output.
        bf16x8 z8 = {0, 0, 0, 0, 0, 0, 0, 0};
        for (int i = tid; i < (EX_BYTES - XCHG_END) / 16; i += 256)
            *(bf16x8*)(smem + EX_OFF + XCHG_END + i * 16) = z8;
    }
    __syncthreads();   // (a) x-tile + bias + EX tail visible to all waves

    int mrowc[4];
#pragma unroll
    for (int t = 0; t < 4; ++t) {
        int m = t * 16 + lane15;
        mrowc[t] = m < 49 ? m : 48;
    }

    bf16x8 fragQ[2][4], fragK[2][4], fragV[2][4];

    // ---- rounds Q and K: GEMM into EX (wave-local columns), capture frags.
    // Wave wv writes exactly cols wv*64..wv*64+63 and captures from the same
    // range -> no cross-wave hazard (SWZ keeps bytes inside the wave's 128-B
    // window per row); within-wave RAW/WAR ordered by lgkmcnt.
    // No barriers in this loop: weight loads stay in flight across rounds.
#pragma unroll
    for (int rnd = 0; rnd < 2; ++rnd) {
        for (int ci = 0; ci < 4; ++ci) {
            int o = (wv * 4 + ci) * 16 + lane15;     // 0..255 (wave-local 64-col slice)
            int orow = rnd * 256 + o;
            f32x4 acc[4];
#pragma unroll
            for (int t = 0; t < 4; ++t) acc[t] = (f32x4){0.f, 0.f, 0.f, 0.f};
#pragma unroll
            for (int ks = 0; ks < 8; ++ks) {
                bf16x8 bfrag = load8(qkv_w, orow * 256 + ks * 32 + quad * 8, isbf);
                int cb = (ks * 32 + quad * 8) * 2;
#pragma unroll
                for (int tm = 0; tm < 4; ++tm) {
                    bf16x8 afrag = *(const bf16x8*)(smem + XO_OFF + mrowc[tm] * 512 + SWZ(mrowc[tm], cb));
                    acc[tm] = __builtin_amdgcn_mfma_f32_16x16x32_bf16(afrag, bfrag, acc[tm], 0, 0, 0);
                }
            }
            float bias = loadf(qkv_b, orow, isbf);
#pragma unroll
            for (int tm = 0; tm < 4; ++tm)
#pragma unroll
                for (int rr = 0; rr < 4; ++rr) {
                    int row = tm * 16 + crow + rr;
                    if (row < 49)
                        *(u16*)(smem + EX_OFF + row * 512 + SWZ(row, o * 2)) = f2b(acc[tm][rr] + bias);
                }
        }
#pragma unroll
        for (int hi = 0; hi < 2; ++hi)
#pragma unroll
            for (int t = 0; t < 4; ++t) {
                int cbyte = wv * 128 + hi * 64 + quad * 16;   // within wave's col slice
                bf16x8 f = *(const bf16x8*)(smem + EX_OFF + mrowc[t] * 512 + SWZ(mrowc[t], cbyte));
                if (rnd == 0) fragQ[hi][t] = f; else fragK[hi][t] = f;
            }
    }
    __syncthreads();   // (b) xchg dead in ALL waves before VT overwrites EX

    // ---- round V: GEMM into EX as V^T [256 ch][stride 56 u16], capture bv.
    // Channels are wave-local (wv*64..+63) for both write and capture.
    for (int ci = 0; ci < 4; ++ci) {
        int vch = (wv * 4 + ci) * 16 + lane15;       // 0..255
        int orow = 512 + vch;
        f32x4 acc[4];
#pragma unroll
        for (int t = 0; t < 4; ++t) acc[t] = (f32x4){0.f, 0.f, 0.f, 0.f};
#pragma unroll
        for (int ks = 0; ks < 8; ++ks) {
            bf16x8 bfrag = load8(qkv_w, orow * 256 + ks * 32 + quad * 8, isbf);
            int cb = (ks * 32 + quad * 8) * 2;
#pragma unroll
            for (int tm = 0; tm < 4; ++tm) {
                bf16x8 afrag = *(const bf16x8*)(smem + XO_OFF + mrowc[tm] * 512 + SWZ(mrowc[tm], cb));
                acc[tm] = __builtin_amdgcn_mfma_f32_16x16x32_bf16(afrag, bfrag, acc[tm], 0, 0, 0);
            }
        }
        float bias = loadf(qkv_b, orow, isbf);
#pragma unroll
        for (int tm = 0; tm < 4; ++tm)
#pragma unroll
            for (int rr = 0; rr < 4; ++rr) {
                int row = tm * 16 + crow + rr;
                if (row < 49)
                    *(u16*)(smem + EX_OFF + (vch * 56 + row) * 2) = f2b(acc[tm][rr] + bias);
            }
    }
#pragma unroll
    for (int hi = 0; hi < 2; ++hi)
#pragma unroll
        for (int f = 0; f < 4; ++f) {
            int vrow = wv * 64 + hi * 32 + (f & 1) * 16 + lane15;
            int vcol = (f >> 1) * 32 + quad * 8;     // cols >=49: stale-finite or zeroed pad
            fragV[hi][f] = *(const bf16x8*)(smem + EX_OFF + (vrow * 56 + vcol) * 2);
        }
    __syncthreads();   // (c) all bv captured before P overwrites EX (P slices
                       //     overlap other waves' VT channel ranges)

    // ---- per-n (column) constants, head-independent ----
    int nval[4], regn_[4], idxn[4];
#pragma unroll
    for (int tn = 0; tn < 4; ++tn) {
        int n = tn * 16 + lane15;
        nval[tn] = (n < 49);
        int nc = n < 49 ? n : 48;
        int rn = DIV7(nc), cn = nc - rn * 7;
        regn_[tn] = region9(whi * 7 + rn, wwi * 7 + cn);
        idxn[tn]  = (6 - rn) * 13 + (6 - cn);
    }

    // ---- attention: 2 heads per wave; P overlays EX (per-wave slice) ----
    char* pbase = smem + EX_OFF + wv * 7056;
#pragma unroll
    for (int hi = 0; hi < 2; ++hi) {
        int h = wv * 2 + hi;
        f32x4 s[4][4];
#pragma unroll
        for (int tm = 0; tm < 4; ++tm)
#pragma unroll
            for (int tn = 0; tn < 4; ++tn) {
                f32x4 z = {0.f, 0.f, 0.f, 0.f};
                s[tm][tn] = __builtin_amdgcn_mfma_f32_16x16x32_bf16(fragQ[hi][tm], fragK[hi][tn], z, 0, 0, 0);
            }
#pragma unroll
        for (int tm = 0; tm < 4; ++tm)
#pragma unroll
            for (int rr = 0; rr < 4; ++rr) {
                int m = tm * 16 + crow + rr;
                int mc2 = m < 49 ? m : 48;
                int rm = DIV7(mc2), cm = mc2 - rm * 7;
                int regm = region9(whi * 7 + rm, wwi * 7 + cm);
                int basem = rm * 13 + cm;
                float e[4];
                float mv = NEGBIG;
#pragma unroll
                for (int tn = 0; tn < 4; ++tn) {
                    float v;
                    if (nval[tn]) {
                        int idx = basem + idxn[tn];
                        float bv = b2f(*(const u16*)(smem + BIAS_OFF + (idx * 8 + h) * 2));
                        v = s[tm][tn][rr] * SCALE + bv + ((regm != regn_[tn]) ? -100.0f : 0.0f);
                    } else v = NEGBIG;
                    e[tn] = v;
                    mv = fmaxf(mv, v);
                }
#pragma unroll
                for (int d = 1; d < 16; d <<= 1) mv = fmaxf(mv, __shfl_xor(mv, d, 16));
                float ssum = 0.f;
#pragma unroll
                for (int tn = 0; tn < 4; ++tn) {
                    e[tn] = __expf(e[tn] - mv);
                    ssum += e[tn];
                }
#pragma unroll
                for (int d = 1; d < 16; d <<= 1) ssum += __shfl_xor(ssum, d, 16);
                float ri = 1.0f / ssum;
                if (m < 49) {
#pragma unroll
                    for (int tn = 0; tn < 4; ++tn) {
                        int n = tn * 16 + lane15;
                        u16 hv = nval[tn] ? f2b(e[tn] * ri) : (u16)0;   // cols 49..63 exact 0
                        *(u16*)(pbase + (m * 72 + n) * 2) = hv;
                    }
                }
            }
        // P is wave-local (pbase per wv); within-wave write->read ordered by
        // lgkmcnt -> no barrier needed before PV.
        f32x4 ov0[4], ov1[4];
#pragma unroll
        for (int tm = 0; tm < 4; ++tm) {
            ov0[tm] = (f32x4){0.f, 0.f, 0.f, 0.f};
            ov1[tm] = (f32x4){0.f, 0.f, 0.f, 0.f};
        }
#pragma unroll
        for (int ks = 0; ks < 2; ++ks) {
            int kb = (ks * 32 + quad * 8) * 2;
#pragma unroll
            for (int tm = 0; tm < 4; ++tm) {
                bf16x8 ap = *(const bf16x8*)(pbase + mrowc[tm] * 144 + kb);
                ov0[tm] = __builtin_amdgcn_mfma_f32_16x16x32_bf16(ap, fragV[hi][ks * 2],     ov0[tm], 0, 0, 0);
                ov1[tm] = __builtin_amdgcn_mfma_f32_16x16x32_bf16(ap, fragV[hi][ks * 2 + 1], ov1[tm], 0, 0, 0);
            }
        }
        // O writes land in wave-local columns h*32..h*32+31 of XO (swizzled).
#pragma unroll
        for (int tm = 0; tm < 4; ++tm)
#pragma unroll
            for (int rr = 0; rr < 4; ++rr) {
                int row = tm * 16 + crow + rr;
                if (row < 49) {
                    *(u16*)(smem + XO_OFF + row * 512 + SWZ(row, (h * 32 + lane15) * 2))        = f2b(ov0[tm][rr]);
                    *(u16*)(smem + XO_OFF + row * 512 + SWZ(row, (h * 32 + 16 + lane15) * 2))   = f2b(ov1[tm][rr]);
                }
            }
    }
    __syncthreads();   // (d) O complete before proj reads all channels

    // ---- proj (transposed): out^T = proj_w x O^T; C rows=out-ch, cols=token ----
    int obase[4];
#pragma unroll
    for (int tn = 0; tn < 4; ++tn) {
        int n = tn * 16 + lane15;
        int nc = n < 49 ? n : 48;
        int rn = DIV7(nc), cn = nc - rn * 7;
        int dh = whi * 7 + rn + 3; if (dh >= 56) dh -= 56;
        int dw = wwi * 7 + cn + 3; if (dw >= 56) dw -= 56;
        obase[tn] = ((b * 56 + dh) * 56 + dw) * 256;
    }
    for (int ci = 0; ci < 4; ++ci) {
        int mch = wv * 4 + ci;                       // out-channel chunk 0..15
        f32x4 acc[4];
#pragma unroll
        for (int t = 0; t < 4; ++t) acc[t] = (f32x4){0.f, 0.f, 0.f, 0.f};
#pragma unroll
        for (int ks = 0; ks < 8; ++ks) {
            bf16x8 af = load8(proj_w, (mch * 16 + lane15) * 256 + ks * 32 + quad * 8, isbf);
            int cb = (ks * 32 + quad * 8) * 2;
#pragma unroll
            for (int tn = 0; tn < 4; ++tn) {
                bf16x8 bo = *(const bf16x8*)(smem + XO_OFF + mrowc[tn] * 512 + SWZ(mrowc[tn], cb));
                acc[tn] = __builtin_amdgcn_mfma_f32_16x16x32_bf16(af, bo, acc[tn], 0, 0, 0);
            }
        }
#pragma unroll
        for (int rr = 0; rr < 4; ++rr) {
            int ch = mch * 16 + crow + rr;           // lane-uniform
            float pb = loadf(proj_b, ch, isbf);
#pragma unroll
            for (int tn = 0; tn < 4; ++tn) {
                if (nval[tn]) {
                    float v = acc[tn][rr] + pb;
                    int oi = obase[tn] + ch;
                    if (isbf) ((u16*)out)[oi] = f2b(v);
                    else      ((float*)out)[oi] = v;
                }
            }
        }
    }
}

extern "C" void kernel_launch(void* const* d_in, const int* in_sizes, int n_in,
                              void* d_out, int out_size, void* d_ws, size_t ws_size,
                              hipStream_t stream) {
    (void)n_in; (void)d_ws; (void)ws_size; (void)out_size;
    int B = in_sizes[0] / (56 * 56 * 256);      // 32
    int nblk = B * 64;                          // one block per window

    swin_fused_v7<<<dim3(nblk), dim3(256), 0, stream>>>(
        d_in[0], d_in[1], d_in[2], d_in[3], d_in[4], d_in[5], d_out);
}